// Round 18
// baseline (392.654 us; speedup 1.0000x reference)
//
#include <hip/hip_runtime.h>
#include <hip/hip_bf16.h>

typedef __bf16 bf16;
typedef __bf16 bf16x2 __attribute__((ext_vector_type(2)));
typedef __bf16 bf16x4 __attribute__((ext_vector_type(4)));
typedef __bf16 bf16x8 __attribute__((ext_vector_type(8)));
typedef float f32x4 __attribute__((ext_vector_type(4)));

#define NF 40
#define HW 256
#define KPAD 384
#define MPAD 48

// ws elem layout (bf16): W3A[18432] | W4A[18432] | W2A[3072] | zrow[1024] |
//                        gated (PLANAR cg-major) | xT NHWC
#define ZROW_ELEM_OFF (2 * MPAD * KPAD + MPAD * 64)          // 39936
#define GATED_ELEM_OFF 40960
#define IMG_ELEMS ((size_t)16 * HW * HW * NF)
#define XT_ELEM_OFF (GATED_ELEM_OFF + IMG_ELEMS)
#define WS_FULL  ((GATED_ELEM_OFF + 2 * IMG_ELEMS) * 2)      // 167.9 MB

// gated planar geometry
#define PLANE ((size_t)HW * HW * 8)
#define IMGSTR ((size_t)HW * HW * NF)

// sweep-step region: 10 rows x 34 cols x 40ch (5 groups of 8ch), 32x8 tile
#define SRW 34
#define SRU 340                   // 16B units per ch-group
#define SGS 2720                  // elems per ch-group (340*8)
#define SNU 1700                  // real units (5*340)
#define SBUF 16384                // elems per buffer (2048 unit slots * 8)

// async global->LDS, 16B per lane; lds base must be wave-uniform
__device__ __forceinline__ void gload_lds16(const bf16* g, bf16* l) {
  __builtin_amdgcn_global_load_lds(
      (const __attribute__((address_space(1))) void*)g,
      (__attribute__((address_space(3))) void*)l, 16, 0, 0);
}

// counted-vmcnt barrier: waits only the prefetch DMAs (loads issued BEFORE the
// epilogue stores; in-order retirement => outstanding<=N guarantees loads done)
#define BARRIER_VM(N)                                                        \
  asm volatile("s_waitcnt vmcnt(" #N ") lgkmcnt(0)\n\ts_barrier" ::: "memory")

// ---------------- weight prep (+ zero row) ----------------
__global__ void prep_weights(const float* __restrict__ w2,
                             const float* __restrict__ w3,
                             const float* __restrict__ w4,
                             bf16* __restrict__ ws) {
  int i = blockIdx.x * 256 + threadIdx.x;
  const int T = MPAD * KPAD;
  if (i < T) {
    int co = i / KPAD, k = i % KPAD;
    float v3 = 0.f, v4 = 0.f;
    if (co < NF && k < 360) {
      int tap = k / NF, ci = k - tap * NF;
      int ky = tap / 3, kx = tap - ky * 3;
      int idx = ((co * NF + ci) * 3 + ky) * 3 + kx;
      v3 = w3[idx];
      v4 = w4[idx];
    }
    ws[i] = (bf16)v3;
    ws[T + i] = (bf16)v4;
  }
  if (i < MPAD * 64) {
    int co = i / 64, ci = i - co * 64;
    float v = 0.f;
    if (co < NF && ci < NF) v = w2[co * NF + ci];
    ws[2 * T + i] = (bf16)v;
  }
  if (i < 1024) ws[ZROW_ELEM_OFF + i] = (bf16)0.f;
}

// ---------------- T: x NCHW f32 -> xT NHWC bf16 ----------------
__global__ __launch_bounds__(256, 8)
void transpose_nhwc(const float* __restrict__ x, bf16* __restrict__ xT) {
  __shared__ bf16 xs[5 * 2056];
  const int tid = threadIdx.x;
  const int row = blockIdx.x;
  const int n   = blockIdx.y;
  const size_t nb = (size_t)n * NF * HW * HW + (size_t)row * HW;

#pragma unroll
  for (int cc = 0; cc < 10; ++cc) {
    bf16x4 v;
#pragma unroll
    for (int j = 0; j < 4; ++j)
      v[j] = (bf16)x[nb + (size_t)(cc * 4 + j) * HW * HW + tid];
    *(bf16x4*)&xs[(cc >> 1) * 2056 + tid * 8 + (cc & 1) * 4] = v;
  }
  __syncthreads();

  const size_t ob = ((size_t)n * HW * HW + (size_t)row * HW) * NF;
#pragma unroll
  for (int k = 0; k < 10; ++k) {
    int u = tid + k * 256;
    int px = u / 10, c4 = u - px * 10;
    bf16x4 v = *(const bf16x4*)&xs[(c4 >> 1) * 2056 + px * 8 + (c4 & 1) * 4];
    *(bf16x4*)&xT[ob + (size_t)u * 4] = v;
  }
}

// ---------------- K1 sweep: 32-col strip, 8 steps of 32x8, 512 thr ---------
// 8 waves: each wave owns ONE output row (2 col-halves) -> 4 waves/SIMD.
__global__ __launch_bounds__(512, 2)
void k1_sweep(const bf16* __restrict__ xT, const float* __restrict__ b2,
              const bf16* __restrict__ ws, bf16* __restrict__ gated) {
  __shared__ bf16 xs[2][SBUF];             // 2 x 32,768 B

  const int tid  = threadIdx.x;
  const int lane = tid & 63;
  const int wid  = tid >> 6;               // 0..7 = output row within step
  const int l15  = lane & 15;
  const int lk   = lane >> 4;
  const int n    = blockIdx.z;
  const int X0   = blockIdx.x * 32;
  const int Yb   = blockIdx.y * 64;
  const bool lasty = (Yb == HW - 64);

  const bf16* W3A  = ws;
  const bf16* W2A  = ws + 2 * MPAD * KPAD;
  const bf16* zrow = ws + ZROW_ELEM_OFF;
  const bf16* bn   = xT + (size_t)n * IMGSTR;

  // ---- loop-invariant precompute
  int gp3[12];
#pragma unroll
  for (int kk = 0; kk < 12; ++kk) {
    int k0 = kk * 32 + lk * 8;
    int kc = (k0 < 360) ? k0 : 0;
    int tap = kc / NF, ci0 = kc - tap * NF;
    int ky = tap / 3, kx = tap - ky * 3;
    gp3[kk] = (ci0 >> 3) * SGS + (ky * SRW + kx) * 8;
  }
  int gctr[2];
#pragma unroll
  for (int kk = 0; kk < 2; ++kk) {
    int k0 = kk * 32 + lk * 8;
    int ci0 = (k0 < NF) ? k0 : 0;
    gctr[kk] = (ci0 >> 3) * SGS + (SRW + 1) * 8;
  }
  int pb[2];
#pragma unroll
  for (int q = 0; q < 2; ++q)
    pb[q] = (wid * SRW + q * 16 + l15) * 8;
  float b2v[3][4];
#pragma unroll
  for (int mt = 0; mt < 3; ++mt)
#pragma unroll
    for (int r = 0; r < 4; ++r) {
      int co = mt * 16 + lk * 4 + r;
      b2v[mt][r] = (co < NF) ? b2[co] : 0.f;
    }
  bf16x8 a2[2][3];
#pragma unroll
  for (int kk = 0; kk < 2; ++kk)
#pragma unroll
    for (int mt = 0; mt < 3; ++mt)
      a2[kk][mt] = *(const bf16x8*)&W2A[(mt * 16 + l15) * 64 + kk * 32 + lk * 8];

  // staging decode (4 units/thread), loop-invariant
  int ur[4], ugx[4], uc8[4], uld[4];
  bool uok[4];
#pragma unroll
  for (int it = 0; it < 4; ++it) {
    int u0 = it * 512 + wid * 64;          // wave-uniform LDS base unit
    int u  = u0 + lane;
    int c   = u / SRU;
    int rem = u - c * SRU;
    int r   = rem / SRW;
    int p   = rem - r * SRW;
    int gx  = X0 - 1 + p;
    uok[it] = (u < SNU) && ((unsigned)gx < HW);
    ur[it]  = (u < SNU) ? r : 0;
    ugx[it] = ((unsigned)gx < HW) ? gx : 0;
    uc8[it] = (u < SNU) ? (c << 3) : 0;
    uld[it] = u0 * 8;
  }

  // incremental prefetch pointers (first prefetch = step1: rows Yb+7+r, in-bounds)
  const bf16* P[4];
#pragma unroll
  for (int it = 0; it < 4; ++it)
    P[it] = uok[it] ? (bn + (size_t)((Yb + 7 + ur[it]) * HW + ugx[it]) * NF + uc8[it])
                    : zrow;
  const size_t PSTEP = (size_t)8 * HW * NF;

  // ---- prologue: stage step 0 (rows Yb-1+r; checked for Yb=0)
  {
    int ys = Yb - 1;
#pragma unroll
    for (int it = 0; it < 4; ++it) {
      int gy = ys + ur[it];
      bool ok = uok[it] && ((unsigned)gy < HW);
      const bf16* src = ok ? (bn + (size_t)(gy * HW + ugx[it]) * NF + uc8[it]) : zrow;
      gload_lds16(src, &xs[0][uld[it]]);
    }
  }
  asm volatile("s_waitcnt vmcnt(0) lgkmcnt(0)\n\ts_barrier" ::: "memory");

  bf16* gbase = gated + (size_t)n * IMGSTR;
  size_t e0 = ((size_t)(Yb + wid) * HW + X0 + l15) * 8;
  const size_t ESTEP = (size_t)8 * HW * 8;

  // ---- 8-step sweep
  for (int s = 0; s < 8; ++s) {
    const bf16* buf = xs[s & 1];

    // 1. issue prefetch for step s+1 (loads FIRST; stores come later)
    if (s < 7) {
      bf16* nbuf = xs[(s & 1) ^ 1];
      if (lasty && s == 6) {
#pragma unroll
        for (int it = 0; it < 4; ++it) {
          bool ok = uok[it] && (ur[it] < 9);
          gload_lds16(ok ? P[it] : zrow, &nbuf[uld[it]]);
        }
      } else {
#pragma unroll
        for (int it = 0; it < 4; ++it) {
          gload_lds16(P[it], &nbuf[uld[it]]);
          P[it] += uok[it] ? PSTEP : 0;
        }
      }
    }
    asm volatile("" ::: "memory");   // pin: DMAs issued before epilogue stores

    // 2. gate GEMM (K=64)
    bf16x4 gv[2][3];
    {
      f32x4 g[2][3];
#pragma unroll
      for (int q = 0; q < 2; ++q)
#pragma unroll
        for (int mt = 0; mt < 3; ++mt) g[q][mt] = f32x4{0, 0, 0, 0};
#pragma unroll
      for (int kk = 0; kk < 2; ++kk)
#pragma unroll
        for (int q = 0; q < 2; ++q) {
          bf16x8 b = *(const bf16x8*)&buf[gctr[kk] + pb[q]];
#pragma unroll
          for (int mt = 0; mt < 3; ++mt)
            g[q][mt] = __builtin_amdgcn_mfma_f32_16x16x32_bf16(a2[kk][mt], b, g[q][mt], 0, 0, 0);
        }
#pragma unroll
      for (int q = 0; q < 2; ++q)
#pragma unroll
        for (int mt = 0; mt < 3; ++mt)
#pragma unroll
          for (int r = 0; r < 4; ++r)
            gv[q][mt][r] = (bf16)(1.f / (1.f + __expf(-(g[q][mt][r] + b2v[mt][r]))));
    }

    // 3. main W3 GEMM (K=384)
    f32x4 f[2][3];
#pragma unroll
    for (int q = 0; q < 2; ++q)
#pragma unroll
      for (int mt = 0; mt < 3; ++mt) f[q][mt] = f32x4{0, 0, 0, 0};

    __builtin_amdgcn_s_setprio(1);
#pragma unroll
    for (int kk = 0; kk < 12; ++kk) {
      bf16x8 a[3];
#pragma unroll
      for (int mt = 0; mt < 3; ++mt)
        a[mt] = *(const bf16x8*)&W3A[(mt * 16 + l15) * KPAD + kk * 32 + lk * 8];
#pragma unroll
      for (int q = 0; q < 2; ++q) {
        bf16x8 b = *(const bf16x8*)&buf[gp3[kk] + pb[q]];
#pragma unroll
        for (int mt = 0; mt < 3; ++mt)
          f[q][mt] = __builtin_amdgcn_mfma_f32_16x16x32_bf16(a[mt], b, f[q][mt], 0, 0, 0);
      }
    }
    __builtin_amdgcn_s_setprio(0);

    // 4. epilogue: gated PLANAR bf16 (6 stores/thread, left in flight)
#pragma unroll
    for (int q = 0; q < 2; ++q) {
      size_t pix8 = e0 + (size_t)(q * 16 * 8);
#pragma unroll
      for (int mt = 0; mt < 3; ++mt) {
        int co0 = mt * 16 + lk * 4;
        if (co0 < NF) {
          int cg = co0 >> 3;
          bf16x4 ov;
#pragma unroll
          for (int r = 0; r < 4; ++r)
            ov[r] = (bf16)(f[q][mt][r] * (float)gv[q][mt][r]);
          *(bf16x4*)&gbase[(size_t)cg * PLANE + pix8 + (co0 & 7)] = ov;
        }
      }
    }
    e0 += ESTEP;

    // 5. counted-vmcnt barrier: waits the 4 DMAs, stores drain async
    BARRIER_VM(6);
  }
}

// ---------------- K2 sweep: out = conv3x3(gated planar, w4), f32 NCHW ------
__global__ __launch_bounds__(512, 2)
void k2_sweep(const bf16* __restrict__ gated, const bf16* __restrict__ ws,
              float* __restrict__ out) {
  __shared__ bf16 xs[2][SBUF];

  const int tid  = threadIdx.x;
  const int lane = tid & 63;
  const int wid  = tid >> 6;
  const int l15  = lane & 15;
  const int lk   = lane >> 4;
  const int n    = blockIdx.z;
  const int X0   = blockIdx.x * 32;
  const int Yb   = blockIdx.y * 64;
  const bool lasty = (Yb == HW - 64);

  const bf16* W4A  = ws + MPAD * KPAD;
  const bf16* zrow = ws + ZROW_ELEM_OFF;
  const bf16* bn   = gated + (size_t)n * IMGSTR;

  int gp4[12];
#pragma unroll
  for (int kk = 0; kk < 12; ++kk) {
    int k0 = kk * 32 + lk * 8;
    int kc = (k0 < 360) ? k0 : 0;
    int tap = kc / NF, ci0 = kc - tap * NF;
    int ky = tap / 3, kx = tap - ky * 3;
    gp4[kk] = (ci0 >> 3) * SGS + (ky * SRW + kx) * 8;
  }
  int pb[2];
#pragma unroll
  for (int q = 0; q < 2; ++q)
    pb[q] = (wid * SRW + q * 16 + l15) * 8;

  int ur[4], ugx[4], ucp[4], uld[4];
  bool uok[4];
#pragma unroll
  for (int it = 0; it < 4; ++it) {
    int u0 = it * 512 + wid * 64;
    int u  = u0 + lane;
    int c   = u / SRU;
    int rem = u - c * SRU;
    int r   = rem / SRW;
    int p   = rem - r * SRW;
    int gx  = X0 - 1 + p;
    uok[it] = (u < SNU) && ((unsigned)gx < HW);
    ur[it]  = (u < SNU) ? r : 0;
    ugx[it] = ((unsigned)gx < HW) ? gx : 0;
    ucp[it] = (u < SNU && c < 5) ? c : 0;
    uld[it] = u0 * 8;
  }

  const bf16* P[4];
#pragma unroll
  for (int it = 0; it < 4; ++it)
    P[it] = uok[it] ? (bn + (size_t)ucp[it] * PLANE +
                       (size_t)((Yb + 7 + ur[it]) * HW + ugx[it]) * 8)
                    : zrow;
  const size_t PSTEP = (size_t)8 * HW * 8;

  {
    int ys = Yb - 1;
#pragma unroll
    for (int it = 0; it < 4; ++it) {
      int gy = ys + ur[it];
      bool ok = uok[it] && ((unsigned)gy < HW);
      const bf16* src = ok ? (bn + (size_t)ucp[it] * PLANE + (size_t)(gy * HW + ugx[it]) * 8)
                           : zrow;
      gload_lds16(src, &xs[0][uld[it]]);
    }
  }
  asm volatile("s_waitcnt vmcnt(0) lgkmcnt(0)\n\ts_barrier" ::: "memory");

  float* on = out + (size_t)n * NF * HW * HW;
  size_t o0 = (size_t)(Yb + wid) * HW + X0 + l15;
  const size_t OSTEP = (size_t)8 * HW;

  for (int s = 0; s < 8; ++s) {
    const bf16* buf = xs[s & 1];

    if (s < 7) {
      bf16* nbuf = xs[(s & 1) ^ 1];
      if (lasty && s == 6) {
#pragma unroll
        for (int it = 0; it < 4; ++it) {
          bool ok = uok[it] && (ur[it] < 9);
          gload_lds16(ok ? P[it] : zrow, &nbuf[uld[it]]);
        }
      } else {
#pragma unroll
        for (int it = 0; it < 4; ++it) {
          gload_lds16(P[it], &nbuf[uld[it]]);
          P[it] += uok[it] ? PSTEP : 0;
        }
      }
    }
    asm volatile("" ::: "memory");

    f32x4 f[2][3];
#pragma unroll
    for (int q = 0; q < 2; ++q)
#pragma unroll
      for (int mt = 0; mt < 3; ++mt) f[q][mt] = f32x4{0, 0, 0, 0};

    __builtin_amdgcn_s_setprio(1);
#pragma unroll
    for (int kk = 0; kk < 12; ++kk) {
      bf16x8 a[3];
#pragma unroll
      for (int mt = 0; mt < 3; ++mt)
        a[mt] = *(const bf16x8*)&W4A[(mt * 16 + l15) * KPAD + kk * 32 + lk * 8];
#pragma unroll
      for (int q = 0; q < 2; ++q) {
        bf16x8 b = *(const bf16x8*)&buf[gp4[kk] + pb[q]];
#pragma unroll
        for (int mt = 0; mt < 3; ++mt)
          f[q][mt] = __builtin_amdgcn_mfma_f32_16x16x32_bf16(a[mt], b, f[q][mt], 0, 0, 0);
      }
    }
    __builtin_amdgcn_s_setprio(0);

    // store f32 NCHW (24 dword stores/thread, left in flight)
#pragma unroll
    for (int q = 0; q < 2; ++q) {
      float* orow = on + o0 + q * 16;
#pragma unroll
      for (int mt = 0; mt < 3; ++mt)
#pragma unroll
        for (int r = 0; r < 4; ++r) {
          int co = mt * 16 + lk * 4 + r;
          if (co < NF)
            orow[(size_t)co * HW * HW] = f[q][mt][r];
        }
    }
    o0 += OSTEP;

    BARRIER_VM(24);
  }
}

// ---------------- fallback K1 (NCHW x staging; writes planar gated) --------
#define K1_RW 18
__global__ __launch_bounds__(512, 6)
void k1_gate_nchw(const float* __restrict__ x, const float* __restrict__ b2,
                  const bf16* __restrict__ ws, bf16* __restrict__ gated) {
  __shared__ bf16 xs[K1_RW * K1_RW * NF];

  const int tid  = threadIdx.x;
  const int lane = tid & 63;
  const int wid  = tid >> 6;
  const int l15  = lane & 15;
  const int lk   = lane >> 4;
  const int n    = blockIdx.z;
  const int X0   = blockIdx.x * 16;
  const int Y0   = blockIdx.y * 16;

  const bf16* W3A = ws;
  const bf16* W2A = ws + 2 * MPAD * KPAD;

  const float* xn = x + (size_t)n * NF * HW * HW;
  for (int i = tid; i < K1_RW * K1_RW * NF / 2; i += 512) {
    int cih = i / (K1_RW * K1_RW);
    int rem = i - cih * (K1_RW * K1_RW);
    int ci  = cih * 2;
    int yy  = rem / K1_RW, xx = rem - yy * K1_RW;
    int gy  = Y0 - 1 + yy, gx = X0 - 1 + xx;
    float v0 = 0.f, v1 = 0.f;
    if ((unsigned)gy < HW && (unsigned)gx < HW) {
      const float* p = xn + (size_t)ci * HW * HW + gy * HW + gx;
      v0 = p[0];
      v1 = p[HW * HW];
    }
    bf16x2 pr; pr[0] = (bf16)v0; pr[1] = (bf16)v1;
    *(bf16x2*)&xs[rem * NF + ci] = pr;
  }

  int off3[12];
#pragma unroll
  for (int kk = 0; kk < 12; ++kk) {
    int k0 = kk * 32 + lk * 8;
    int kc = (k0 < 360) ? k0 : 0;
    int tap = kc / NF, ci0 = kc - tap * NF;
    int ky = tap / 3, kx = tap - ky * 3;
    off3[kk] = (ky * K1_RW + kx) * NF + ci0;
  }
  int pb[2];
#pragma unroll
  for (int t2 = 0; t2 < 2; ++t2) {
    int pix = (wid * 2 + t2) * 16 + l15;
    int py = pix >> 4, px = pix & 15;
    pb[t2] = (py * K1_RW + px) * NF;
  }
  float b2v[3][4];
#pragma unroll
  for (int mt = 0; mt < 3; ++mt)
#pragma unroll
    for (int r = 0; r < 4; ++r) {
      int co = mt * 16 + lk * 4 + r;
      b2v[mt][r] = (co < NF) ? b2[co] : 0.f;
    }

  __syncthreads();

  bf16x4 gv[2][3];
  {
    f32x4 g[2][3];
#pragma unroll
    for (int t2 = 0; t2 < 2; ++t2)
#pragma unroll
      for (int mt = 0; mt < 3; ++mt) g[t2][mt] = f32x4{0, 0, 0, 0};
#pragma unroll
    for (int kk = 0; kk < 2; ++kk) {
      int k0 = kk * 32 + lk * 8;
      int goff = (K1_RW + 1) * NF + ((k0 < NF) ? k0 : 0);
      bf16x8 a[3];
#pragma unroll
      for (int mt = 0; mt < 3; ++mt)
        a[mt] = *(const bf16x8*)&W2A[(mt * 16 + l15) * 64 + k0];
#pragma unroll
      for (int t2 = 0; t2 < 2; ++t2) {
        bf16x8 b = *(const bf16x8*)&xs[pb[t2] + goff];
#pragma unroll
        for (int mt = 0; mt < 3; ++mt)
          g[t2][mt] = __builtin_amdgcn_mfma_f32_16x16x32_bf16(a[mt], b, g[t2][mt], 0, 0, 0);
      }
    }
#pragma unroll
    for (int t2 = 0; t2 < 2; ++t2)
#pragma unroll
      for (int mt = 0; mt < 3; ++mt)
#pragma unroll
        for (int r = 0; r < 4; ++r)
          gv[t2][mt][r] = (bf16)(1.f / (1.f + __expf(-(g[t2][mt][r] + b2v[mt][r]))));
  }

  f32x4 facc[2][3];
#pragma unroll
  for (int t2 = 0; t2 < 2; ++t2)
#pragma unroll
    for (int mt = 0; mt < 3; ++mt) facc[t2][mt] = f32x4{0, 0, 0, 0};

#pragma unroll
  for (int kk = 0; kk < 12; ++kk) {
    bf16x8 a[3];
#pragma unroll
    for (int mt = 0; mt < 3; ++mt)
      a[mt] = *(const bf16x8*)&W3A[(mt * 16 + l15) * KPAD + kk * 32 + lk * 8];
#pragma unroll
    for (int t2 = 0; t2 < 2; ++t2) {
      bf16x8 b = *(const bf16x8*)&xs[pb[t2] + off3[kk]];
#pragma unroll
      for (int mt = 0; mt < 3; ++mt)
        facc[t2][mt] = __builtin_amdgcn_mfma_f32_16x16x32_bf16(a[mt], b, facc[t2][mt], 0, 0, 0);
    }
  }

#pragma unroll
  for (int t2 = 0; t2 < 2; ++t2) {
    int pix = (wid * 2 + t2) * 16 + l15;
    int py = pix >> 4, px = pix & 15;
    size_t pix8 = ((size_t)(Y0 + py) * HW + (X0 + px)) * 8;
#pragma unroll
    for (int mt = 0; mt < 3; ++mt) {
      int co0 = mt * 16 + lk * 4;
      if (co0 < NF) {
        int cg = co0 >> 3;
        bf16x4 ov;
#pragma unroll
        for (int r = 0; r < 4; ++r)
          ov[r] = (bf16)(facc[t2][mt][r] * (float)gv[t2][mt][r]);
        *(bf16x4*)&gated[(size_t)n * IMGSTR + (size_t)cg * PLANE + pix8 + (co0 & 7)] = ov;
      }
    }
  }
}

extern "C" void kernel_launch(void* const* d_in, const int* in_sizes, int n_in,
                              void* d_out, int out_size, void* d_ws, size_t ws_size,
                              hipStream_t stream) {
  const float* x  = (const float*)d_in[0];
  const float* w2 = (const float*)d_in[1];
  const float* b2 = (const float*)d_in[2];
  const float* w3 = (const float*)d_in[3];
  const float* w4 = (const float*)d_in[4];
  float* out = (float*)d_out;
  bf16* ws   = (bf16*)d_ws;

  hipLaunchKernelGGL(prep_weights, dim3(72), dim3(256), 0, stream, w2, w3, w4, ws);

  bf16* gated = ws + GATED_ELEM_OFF;
  if (ws_size >= WS_FULL) {
    bf16* xT = ws + XT_ELEM_OFF;
    hipLaunchKernelGGL(transpose_nhwc, dim3(256, 16), dim3(256), 0, stream, x, xT);
    hipLaunchKernelGGL(k1_sweep, dim3(8, 4, 16), dim3(512), 0, stream,
                       xT, b2, ws, gated);
  } else {
    hipLaunchKernelGGL(k1_gate_nchw, dim3(16, 16, 16), dim3(512), 0, stream,
                       x, b2, ws, gated);
  }
  hipLaunchKernelGGL(k2_sweep, dim3(8, 4, 16), dim3(512), 0, stream,
                     gated, ws, out);
}

// Round 19
// 250.935 us; speedup vs baseline: 1.5648x; 1.5648x over previous
//
#include <hip/hip_runtime.h>
#include <hip/hip_bf16.h>

typedef __bf16 bf16;
typedef __bf16 bf16x2 __attribute__((ext_vector_type(2)));
typedef __bf16 bf16x4 __attribute__((ext_vector_type(4)));
typedef __bf16 bf16x8 __attribute__((ext_vector_type(8)));
typedef float f32x4 __attribute__((ext_vector_type(4)));

#define NF 40
#define HW 256
#define KPAD 384
#define MPAD 48

// ws elem layout (bf16): W3A[18432] | W4A[18432] | W2A[3072] | zrow[1024] |
//                        gated (PLANAR cg-major) | xT NHWC
#define ZROW_ELEM_OFF (2 * MPAD * KPAD + MPAD * 64)          // 39936
#define GATED_ELEM_OFF 40960
#define IMG_ELEMS ((size_t)16 * HW * HW * NF)
#define XT_ELEM_OFF (GATED_ELEM_OFF + IMG_ELEMS)
#define WS_FULL  ((GATED_ELEM_OFF + 2 * IMG_ELEMS) * 2)      // 167.9 MB

// gated planar geometry
#define PLANE ((size_t)HW * HW * 8)
#define IMGSTR ((size_t)HW * HW * NF)

// sweep-step region: 10 rows x 34 cols x 40ch (5 groups of 8ch), 32x8 tile
#define SRW 34
#define SRU 340                   // 16B units per ch-group
#define SGS 2720                  // elems per ch-group (340*8)
#define SNU 1700                  // real units (5*340)
#define SBUF 14336                // elems per buffer (1792 units * 8)

// async global->LDS, 16B per lane; lds base must be wave-uniform
__device__ __forceinline__ void gload_lds16(const bf16* g, bf16* l) {
  __builtin_amdgcn_global_load_lds(
      (const __attribute__((address_space(1))) void*)g,
      (__attribute__((address_space(3))) void*)l, 16, 0, 0);
}

// counted-vmcnt barrier: waits only the prefetch DMAs (loads issued BEFORE the
// epilogue stores; in-order retirement => outstanding<=N guarantees loads done)
#define BARRIER_VM(N)                                                        \
  asm volatile("s_waitcnt vmcnt(" #N ") lgkmcnt(0)\n\ts_barrier" ::: "memory")

// XCD-chunked bijective swizzle: logical block l = bands of 8 x-strips that
// share a 66-row xT band land on ONE XCD (default mapping put them on 8).
// bid -> l: a=bid&7 (XCD), b=(bid>>3)&7, c=bid>>6;  l = 8a + b + 64c
__device__ __forceinline__ int swz_block(int bid) {
  return ((bid & 7) << 3) + ((bid >> 3) & 7) + (bid & ~63);
}

// ---------------- weight prep (+ zero row) ----------------
__global__ void prep_weights(const float* __restrict__ w2,
                             const float* __restrict__ w3,
                             const float* __restrict__ w4,
                             bf16* __restrict__ ws) {
  int i = blockIdx.x * 256 + threadIdx.x;
  const int T = MPAD * KPAD;
  if (i < T) {
    int co = i / KPAD, k = i % KPAD;
    float v3 = 0.f, v4 = 0.f;
    if (co < NF && k < 360) {
      int tap = k / NF, ci = k - tap * NF;
      int ky = tap / 3, kx = tap - ky * 3;
      int idx = ((co * NF + ci) * 3 + ky) * 3 + kx;
      v3 = w3[idx];
      v4 = w4[idx];
    }
    ws[i] = (bf16)v3;
    ws[T + i] = (bf16)v4;
  }
  if (i < MPAD * 64) {
    int co = i / 64, ci = i - co * 64;
    float v = 0.f;
    if (co < NF && ci < NF) v = w2[co * NF + ci];
    ws[2 * T + i] = (bf16)v;
  }
  if (i < 1024) ws[ZROW_ELEM_OFF + i] = (bf16)0.f;
}

// ---------------- T: x NCHW f32 -> xT NHWC bf16 ----------------
__global__ __launch_bounds__(256, 8)
void transpose_nhwc(const float* __restrict__ x, bf16* __restrict__ xT) {
  __shared__ bf16 xs[5 * 2056];
  const int tid = threadIdx.x;
  const int row = blockIdx.x;
  const int n   = blockIdx.y;
  const size_t nb = (size_t)n * NF * HW * HW + (size_t)row * HW;

#pragma unroll
  for (int cc = 0; cc < 10; ++cc) {
    bf16x4 v;
#pragma unroll
    for (int j = 0; j < 4; ++j)
      v[j] = (bf16)x[nb + (size_t)(cc * 4 + j) * HW * HW + tid];
    *(bf16x4*)&xs[(cc >> 1) * 2056 + tid * 8 + (cc & 1) * 4] = v;
  }
  __syncthreads();

  const size_t ob = ((size_t)n * HW * HW + (size_t)row * HW) * NF;
#pragma unroll
  for (int k = 0; k < 10; ++k) {
    int u = tid + k * 256;
    int px = u / 10, c4 = u - px * 10;
    bf16x4 v = *(const bf16x4*)&xs[(c4 >> 1) * 2056 + px * 8 + (c4 & 1) * 4];
    *(bf16x4*)&xT[ob + (size_t)u * 4] = v;
  }
}

// ---------------- K1 sweep: persistent 32-col strip, 8 steps of 32x8 -------
__global__ __launch_bounds__(256, 2)
void k1_sweep(const bf16* __restrict__ xT, const float* __restrict__ b2,
              const bf16* __restrict__ ws, bf16* __restrict__ gated) {
  __shared__ bf16 xs[2][SBUF];             // 2 x 28,672 B

  const int tid  = threadIdx.x;
  const int lane = tid & 63;
  const int wid  = tid >> 6;               // 0..3
  const int l15  = lane & 15;
  const int lk   = lane >> 4;
  const int l    = swz_block(blockIdx.x);  // XCD-chunked decode
  const int n    = l >> 5;
  const int X0   = (l & 7) * 32;
  const int Yb   = ((l >> 3) & 3) * 64;
  const bool lasty = (Yb == HW - 64);

  const bf16* W3A  = ws;
  const bf16* W2A  = ws + 2 * MPAD * KPAD;
  const bf16* zrow = ws + ZROW_ELEM_OFF;
  const bf16* bn   = xT + (size_t)n * IMGSTR;

  // ---- loop-invariant precompute
  int gp3[12];
#pragma unroll
  for (int kk = 0; kk < 12; ++kk) {
    int k0 = kk * 32 + lk * 8;
    int kc = (k0 < 360) ? k0 : 0;
    int tap = kc / NF, ci0 = kc - tap * NF;
    int ky = tap / 3, kx = tap - ky * 3;
    gp3[kk] = (ci0 >> 3) * SGS + (ky * SRW + kx) * 8;
  }
  int gctr[2];
#pragma unroll
  for (int kk = 0; kk < 2; ++kk) {
    int k0 = kk * 32 + lk * 8;
    int ci0 = (k0 < NF) ? k0 : 0;
    gctr[kk] = (ci0 >> 3) * SGS + (SRW + 1) * 8;
  }
  int pb[4];
#pragma unroll
  for (int q = 0; q < 4; ++q)
    pb[q] = ((wid * 2 + (q >> 1)) * SRW + (q & 1) * 16 + l15) * 8;
  float b2v[3][4];
#pragma unroll
  for (int mt = 0; mt < 3; ++mt)
#pragma unroll
    for (int r = 0; r < 4; ++r) {
      int co = mt * 16 + lk * 4 + r;
      b2v[mt][r] = (co < NF) ? b2[co] : 0.f;
    }
  bf16x8 a2[2][3];
#pragma unroll
  for (int kk = 0; kk < 2; ++kk)
#pragma unroll
    for (int mt = 0; mt < 3; ++mt)
      a2[kk][mt] = *(const bf16x8*)&W2A[(mt * 16 + l15) * 64 + kk * 32 + lk * 8];

  // staging decode (7 units/thread), loop-invariant
  int ur[7], ugx[7], uc8[7], uld[7];
  bool uok[7];
#pragma unroll
  for (int it = 0; it < 7; ++it) {
    int u0 = it * 256 + wid * 64;
    int u  = u0 + lane;
    int c   = u / SRU;
    int rem = u - c * SRU;
    int r   = rem / SRW;
    int p   = rem - r * SRW;
    int gx  = X0 - 1 + p;
    uok[it] = (u < SNU) && ((unsigned)gx < HW);
    ur[it]  = r;
    ugx[it] = ((unsigned)gx < HW) ? gx : 0;
    uc8[it] = (c << 3);
    uld[it] = u0 * 8;
  }

  // incremental prefetch pointers (first prefetch = step1: rows Yb+7+r, in-bounds)
  const bf16* P[7];
#pragma unroll
  for (int it = 0; it < 7; ++it)
    P[it] = uok[it] ? (bn + (size_t)((Yb + 7 + ur[it]) * HW + ugx[it]) * NF + uc8[it])
                    : zrow;
  const size_t PSTEP = (size_t)8 * HW * NF;

  // ---- prologue: stage step 0 (rows Yb-1+r; checked for Yb=0)
  {
    int ys = Yb - 1;
#pragma unroll
    for (int it = 0; it < 7; ++it) {
      int gy = ys + ur[it];
      bool ok = uok[it] && ((unsigned)gy < HW);
      const bf16* src = ok ? (bn + (size_t)(gy * HW + ugx[it]) * NF + uc8[it]) : zrow;
      gload_lds16(src, &xs[0][uld[it]]);
    }
  }
  asm volatile("s_waitcnt vmcnt(0) lgkmcnt(0)\n\ts_barrier" ::: "memory");

  bf16* gbase = gated + (size_t)n * IMGSTR;
  size_t e0 = ((size_t)(Yb + wid * 2) * HW + X0 + l15) * 8;
  const size_t ESTEP = (size_t)8 * HW * 8;

  // ---- 8-step sweep
  for (int s = 0; s < 8; ++s) {
    const bf16* buf = xs[s & 1];

    // 1. issue prefetch for step s+1 (loads FIRST; stores come later)
    if (s < 7) {
      bf16* nbuf = xs[(s & 1) ^ 1];
      if (lasty && s == 6) {
#pragma unroll
        for (int it = 0; it < 7; ++it) {
          bool ok = uok[it] && (ur[it] < 9);
          gload_lds16(ok ? P[it] : zrow, &nbuf[uld[it]]);
        }
      } else {
#pragma unroll
        for (int it = 0; it < 7; ++it) {
          gload_lds16(P[it], &nbuf[uld[it]]);
          P[it] += uok[it] ? PSTEP : 0;
        }
      }
    }
    asm volatile("" ::: "memory");   // pin: DMAs issued before epilogue stores

    // 2. gate GEMM (K=64)
    bf16x4 gv[4][3];
    {
      f32x4 g[4][3];
#pragma unroll
      for (int q = 0; q < 4; ++q)
#pragma unroll
        for (int mt = 0; mt < 3; ++mt) g[q][mt] = f32x4{0, 0, 0, 0};
#pragma unroll
      for (int kk = 0; kk < 2; ++kk)
#pragma unroll
        for (int q = 0; q < 4; ++q) {
          bf16x8 b = *(const bf16x8*)&buf[gctr[kk] + pb[q]];
#pragma unroll
          for (int mt = 0; mt < 3; ++mt)
            g[q][mt] = __builtin_amdgcn_mfma_f32_16x16x32_bf16(a2[kk][mt], b, g[q][mt], 0, 0, 0);
        }
#pragma unroll
      for (int q = 0; q < 4; ++q)
#pragma unroll
        for (int mt = 0; mt < 3; ++mt)
#pragma unroll
          for (int r = 0; r < 4; ++r)
            gv[q][mt][r] = (bf16)(1.f / (1.f + __expf(-(g[q][mt][r] + b2v[mt][r]))));
    }

    // 3. main W3 GEMM (K=384)
    f32x4 f[4][3];
#pragma unroll
    for (int q = 0; q < 4; ++q)
#pragma unroll
      for (int mt = 0; mt < 3; ++mt) f[q][mt] = f32x4{0, 0, 0, 0};

    __builtin_amdgcn_s_setprio(1);
#pragma unroll
    for (int kk = 0; kk < 12; ++kk) {
      bf16x8 a[3];
#pragma unroll
      for (int mt = 0; mt < 3; ++mt)
        a[mt] = *(const bf16x8*)&W3A[(mt * 16 + l15) * KPAD + kk * 32 + lk * 8];
#pragma unroll
      for (int q = 0; q < 4; ++q) {
        bf16x8 b = *(const bf16x8*)&buf[gp3[kk] + pb[q]];
#pragma unroll
        for (int mt = 0; mt < 3; ++mt)
          f[q][mt] = __builtin_amdgcn_mfma_f32_16x16x32_bf16(a[mt], b, f[q][mt], 0, 0, 0);
      }
    }
    __builtin_amdgcn_s_setprio(0);

    // 4. epilogue: gated PLANAR bf16 (12 stores/wave, left in flight)
#pragma unroll
    for (int q = 0; q < 4; ++q) {
      size_t pix8 = e0 + (size_t)(((q >> 1) * HW + (q & 1) * 16) * 8);
#pragma unroll
      for (int mt = 0; mt < 3; ++mt) {
        int co0 = mt * 16 + lk * 4;
        if (co0 < NF) {
          int cg = co0 >> 3;
          bf16x4 ov;
#pragma unroll
          for (int r = 0; r < 4; ++r)
            ov[r] = (bf16)(f[q][mt][r] * (float)gv[q][mt][r]);
          *(bf16x4*)&gbase[(size_t)cg * PLANE + pix8 + (co0 & 7)] = ov;
        }
      }
    }
    e0 += ESTEP;

    // 5. tight counted-vmcnt barrier: 12 stores newer than the 7 loads
    BARRIER_VM(12);
  }
}

// ---------------- K2 sweep: out = conv3x3(gated planar, w4), f32 NCHW ------
__global__ __launch_bounds__(256, 2)
void k2_sweep(const bf16* __restrict__ gated, const bf16* __restrict__ ws,
              float* __restrict__ out) {
  __shared__ bf16 xs[2][SBUF];

  const int tid  = threadIdx.x;
  const int lane = tid & 63;
  const int wid  = tid >> 6;
  const int l15  = lane & 15;
  const int lk   = lane >> 4;
  const int l    = swz_block(blockIdx.x);
  const int n    = l >> 5;
  const int X0   = (l & 7) * 32;
  const int Yb   = ((l >> 3) & 3) * 64;
  const bool lasty = (Yb == HW - 64);

  const bf16* W4A  = ws + MPAD * KPAD;
  const bf16* zrow = ws + ZROW_ELEM_OFF;
  const bf16* bn   = gated + (size_t)n * IMGSTR;

  int gp4[12];
#pragma unroll
  for (int kk = 0; kk < 12; ++kk) {
    int k0 = kk * 32 + lk * 8;
    int kc = (k0 < 360) ? k0 : 0;
    int tap = kc / NF, ci0 = kc - tap * NF;
    int ky = tap / 3, kx = tap - ky * 3;
    gp4[kk] = (ci0 >> 3) * SGS + (ky * SRW + kx) * 8;
  }
  int pb[4];
#pragma unroll
  for (int q = 0; q < 4; ++q)
    pb[q] = ((wid * 2 + (q >> 1)) * SRW + (q & 1) * 16 + l15) * 8;

  int ur[7], ugx[7], ucp[7], uld[7];
  bool uok[7];
#pragma unroll
  for (int it = 0; it < 7; ++it) {
    int u0 = it * 256 + wid * 64;
    int u  = u0 + lane;
    int c   = u / SRU;
    int rem = u - c * SRU;
    int r   = rem / SRW;
    int p   = rem - r * SRW;
    int gx  = X0 - 1 + p;
    uok[it] = (u < SNU) && ((unsigned)gx < HW);
    ur[it]  = r;
    ugx[it] = ((unsigned)gx < HW) ? gx : 0;
    ucp[it] = (c < 5) ? c : 0;
    uld[it] = u0 * 8;
  }

  const bf16* P[7];
#pragma unroll
  for (int it = 0; it < 7; ++it)
    P[it] = uok[it] ? (bn + (size_t)ucp[it] * PLANE +
                       (size_t)((Yb + 7 + ur[it]) * HW + ugx[it]) * 8)
                    : zrow;
  const size_t PSTEP = (size_t)8 * HW * 8;

  {
    int ys = Yb - 1;
#pragma unroll
    for (int it = 0; it < 7; ++it) {
      int gy = ys + ur[it];
      bool ok = uok[it] && ((unsigned)gy < HW);
      const bf16* src = ok ? (bn + (size_t)ucp[it] * PLANE + (size_t)(gy * HW + ugx[it]) * 8)
                           : zrow;
      gload_lds16(src, &xs[0][uld[it]]);
    }
  }
  asm volatile("s_waitcnt vmcnt(0) lgkmcnt(0)\n\ts_barrier" ::: "memory");

  float* on = out + (size_t)n * NF * HW * HW;
  size_t o0 = (size_t)(Yb + wid * 2) * HW + X0 + l15;
  const size_t OSTEP = (size_t)8 * HW;

  for (int s = 0; s < 8; ++s) {
    const bf16* buf = xs[s & 1];

    if (s < 7) {
      bf16* nbuf = xs[(s & 1) ^ 1];
      if (lasty && s == 6) {
#pragma unroll
        for (int it = 0; it < 7; ++it) {
          bool ok = uok[it] && (ur[it] < 9);
          gload_lds16(ok ? P[it] : zrow, &nbuf[uld[it]]);
        }
      } else {
#pragma unroll
        for (int it = 0; it < 7; ++it) {
          gload_lds16(P[it], &nbuf[uld[it]]);
          P[it] += uok[it] ? PSTEP : 0;
        }
      }
    }
    asm volatile("" ::: "memory");

    f32x4 f[4][3];
#pragma unroll
    for (int q = 0; q < 4; ++q)
#pragma unroll
      for (int mt = 0; mt < 3; ++mt) f[q][mt] = f32x4{0, 0, 0, 0};

    __builtin_amdgcn_s_setprio(1);
#pragma unroll
    for (int kk = 0; kk < 12; ++kk) {
      bf16x8 a[3];
#pragma unroll
      for (int mt = 0; mt < 3; ++mt)
        a[mt] = *(const bf16x8*)&W4A[(mt * 16 + l15) * KPAD + kk * 32 + lk * 8];
#pragma unroll
      for (int q = 0; q < 4; ++q) {
        bf16x8 b = *(const bf16x8*)&buf[gp4[kk] + pb[q]];
#pragma unroll
        for (int mt = 0; mt < 3; ++mt)
          f[q][mt] = __builtin_amdgcn_mfma_f32_16x16x32_bf16(a[mt], b, f[q][mt], 0, 0, 0);
      }
    }
    __builtin_amdgcn_s_setprio(0);

    // store f32 NCHW (48 dword stores/wave, left in flight)
#pragma unroll
    for (int q = 0; q < 4; ++q) {
      float* orow = on + o0 + ((q >> 1) * HW + (q & 1) * 16);
#pragma unroll
      for (int mt = 0; mt < 3; ++mt)
#pragma unroll
        for (int r = 0; r < 4; ++r) {
          int co = mt * 16 + lk * 4 + r;
          if (co < NF)
            orow[(size_t)co * HW * HW] = f[q][mt][r];
        }
    }
    o0 += OSTEP;

    // tight: 48 stores newer than the 7 loads
    BARRIER_VM(48);
  }
}

// ---------------- fallback K1 (NCHW x staging; writes planar gated) --------
#define K1_RW 18
__global__ __launch_bounds__(512, 6)
void k1_gate_nchw(const float* __restrict__ x, const float* __restrict__ b2,
                  const bf16* __restrict__ ws, bf16* __restrict__ gated) {
  __shared__ bf16 xs[K1_RW * K1_RW * NF];

  const int tid  = threadIdx.x;
  const int lane = tid & 63;
  const int wid  = tid >> 6;
  const int l15  = lane & 15;
  const int lk   = lane >> 4;
  const int n    = blockIdx.z;
  const int X0   = blockIdx.x * 16;
  const int Y0   = blockIdx.y * 16;

  const bf16* W3A = ws;
  const bf16* W2A = ws + 2 * MPAD * KPAD;

  const float* xn = x + (size_t)n * NF * HW * HW;
  for (int i = tid; i < K1_RW * K1_RW * NF / 2; i += 512) {
    int cih = i / (K1_RW * K1_RW);
    int rem = i - cih * (K1_RW * K1_RW);
    int ci  = cih * 2;
    int yy  = rem / K1_RW, xx = rem - yy * K1_RW;
    int gy  = Y0 - 1 + yy, gx = X0 - 1 + xx;
    float v0 = 0.f, v1 = 0.f;
    if ((unsigned)gy < HW && (unsigned)gx < HW) {
      const float* p = xn + (size_t)ci * HW * HW + gy * HW + gx;
      v0 = p[0];
      v1 = p[HW * HW];
    }
    bf16x2 pr; pr[0] = (bf16)v0; pr[1] = (bf16)v1;
    *(bf16x2*)&xs[rem * NF + ci] = pr;
  }

  int off3[12];
#pragma unroll
  for (int kk = 0; kk < 12; ++kk) {
    int k0 = kk * 32 + lk * 8;
    int kc = (k0 < 360) ? k0 : 0;
    int tap = kc / NF, ci0 = kc - tap * NF;
    int ky = tap / 3, kx = tap - ky * 3;
    off3[kk] = (ky * K1_RW + kx) * NF + ci0;
  }
  int pb[2];
#pragma unroll
  for (int t2 = 0; t2 < 2; ++t2) {
    int pix = (wid * 2 + t2) * 16 + l15;
    int py = pix >> 4, px = pix & 15;
    pb[t2] = (py * K1_RW + px) * NF;
  }
  float b2v[3][4];
#pragma unroll
  for (int mt = 0; mt < 3; ++mt)
#pragma unroll
    for (int r = 0; r < 4; ++r) {
      int co = mt * 16 + lk * 4 + r;
      b2v[mt][r] = (co < NF) ? b2[co] : 0.f;
    }

  __syncthreads();

  bf16x4 gv[2][3];
  {
    f32x4 g[2][3];
#pragma unroll
    for (int t2 = 0; t2 < 2; ++t2)
#pragma unroll
      for (int mt = 0; mt < 3; ++mt) g[t2][mt] = f32x4{0, 0, 0, 0};
#pragma unroll
    for (int kk = 0; kk < 2; ++kk) {
      int k0 = kk * 32 + lk * 8;
      int goff = (K1_RW + 1) * NF + ((k0 < NF) ? k0 : 0);
      bf16x8 a[3];
#pragma unroll
      for (int mt = 0; mt < 3; ++mt)
        a[mt] = *(const bf16x8*)&W2A[(mt * 16 + l15) * 64 + k0];
#pragma unroll
      for (int t2 = 0; t2 < 2; ++t2) {
        bf16x8 b = *(const bf16x8*)&xs[pb[t2] + goff];
#pragma unroll
        for (int mt = 0; mt < 3; ++mt)
          g[t2][mt] = __builtin_amdgcn_mfma_f32_16x16x32_bf16(a[mt], b, g[t2][mt], 0, 0, 0);
      }
    }
#pragma unroll
    for (int t2 = 0; t2 < 2; ++t2)
#pragma unroll
      for (int mt = 0; mt < 3; ++mt)
#pragma unroll
        for (int r = 0; r < 4; ++r)
          gv[t2][mt][r] = (bf16)(1.f / (1.f + __expf(-(g[t2][mt][r] + b2v[mt][r]))));
  }

  f32x4 facc[2][3];
#pragma unroll
  for (int t2 = 0; t2 < 2; ++t2)
#pragma unroll
    for (int mt = 0; mt < 3; ++mt) facc[t2][mt] = f32x4{0, 0, 0, 0};

#pragma unroll
  for (int kk = 0; kk < 12; ++kk) {
    bf16x8 a[3];
#pragma unroll
    for (int mt = 0; mt < 3; ++mt)
      a[mt] = *(const bf16x8*)&W3A[(mt * 16 + l15) * KPAD + kk * 32 + lk * 8];
#pragma unroll
    for (int t2 = 0; t2 < 2; ++t2) {
      bf16x8 b = *(const bf16x8*)&xs[pb[t2] + off3[kk]];
#pragma unroll
      for (int mt = 0; mt < 3; ++mt)
        facc[t2][mt] = __builtin_amdgcn_mfma_f32_16x16x32_bf16(a[mt], b, facc[t2][mt], 0, 0, 0);
    }
  }

#pragma unroll
  for (int t2 = 0; t2 < 2; ++t2) {
    int pix = (wid * 2 + t2) * 16 + l15;
    int py = pix >> 4, px = pix & 15;
    size_t pix8 = ((size_t)(Y0 + py) * HW + (X0 + px)) * 8;
#pragma unroll
    for (int mt = 0; mt < 3; ++mt) {
      int co0 = mt * 16 + lk * 4;
      if (co0 < NF) {
        int cg = co0 >> 3;
        bf16x4 ov;
#pragma unroll
        for (int r = 0; r < 4; ++r)
          ov[r] = (bf16)(facc[t2][mt][r] * (float)gv[t2][mt][r]);
        *(bf16x4*)&gated[(size_t)n * IMGSTR + (size_t)cg * PLANE + pix8 + (co0 & 7)] = ov;
      }
    }
  }
}

extern "C" void kernel_launch(void* const* d_in, const int* in_sizes, int n_in,
                              void* d_out, int out_size, void* d_ws, size_t ws_size,
                              hipStream_t stream) {
  const float* x  = (const float*)d_in[0];
  const float* w2 = (const float*)d_in[1];
  const float* b2 = (const float*)d_in[2];
  const float* w3 = (const float*)d_in[3];
  const float* w4 = (const float*)d_in[4];
  float* out = (float*)d_out;
  bf16* ws   = (bf16*)d_ws;

  hipLaunchKernelGGL(prep_weights, dim3(72), dim3(256), 0, stream, w2, w3, w4, ws);

  bf16* gated = ws + GATED_ELEM_OFF;
  if (ws_size >= WS_FULL) {
    bf16* xT = ws + XT_ELEM_OFF;
    hipLaunchKernelGGL(transpose_nhwc, dim3(256, 16), dim3(256), 0, stream, x, xT);
    hipLaunchKernelGGL(k1_sweep, dim3(512), dim3(256), 0, stream,
                       xT, b2, ws, gated);
  } else {
    hipLaunchKernelGGL(k1_gate_nchw, dim3(16, 16, 16), dim3(512), 0, stream,
                       x, b2, ws, gated);
  }
  hipLaunchKernelGGL(k2_sweep, dim3(512), dim3(256), 0, stream,
                     gated, ws, out);
}